// Round 1
// 188.123 us; speedup vs baseline: 1.0177x; 1.0177x over previous
//
#include <hip/hip_runtime.h>

// Problem constants: A=1, B=8, M=256, H=2048, E=8, K=2, N=2048
#define Bn 8
#define Mn 256
#define Hn 2048
#define En 8
#define Kn 2
#define Nn 2048

typedef float vf4 __attribute__((ext_vector_type(4)));

// d_ws layout:
//   hsp [2][Bn][Hn] floats (128 KB) -- hidden column sums, split in two m-halves
//   wsum[En][Hn]    floats (64 KB)  -- gate_up_proj row sums
//
// Grid: 2304 blocks x 128 threads == exactly 9 blocks/CU on 256 CUs, and every
// block streams exactly 64 KB (uniform work) -> no 4.5-blocks/CU drain tail.
//   blocks [0,256):    hidden partial column sums. block = (b, kh, mh):
//                      b in [0,8), kh = 128-float h-slice in [0,16), mh = m-half.
//                      128 rows x 128 floats = 64 KB -> hsp[mh][b][kh*128..]
//   blocks [256,2304): gup row sums. 2 waves/block, wave owns 4 consecutive
//                      rows, prefetch row j+1's 8 float4 loads while reducing
//                      row j. Nontemporal (single-use stream).
__global__ void __launch_bounds__(128, 5) reduce_kernel(
        const float* __restrict__ hidden,
        const float* __restrict__ gup,
        float* __restrict__ hsp,
        float* __restrict__ wsum) {
    const int bid = blockIdx.x;
    const int t   = threadIdx.x;
    if (bid < 256) {
        const int b   = bid >> 5;
        const int kh  = (bid >> 1) & 15;
        const int mh  = bid & 1;
        const int col = t & 31;          // float4 column within 128-float slice
        const int mg  = t >> 5;          // m-group: 4 groups x 32 rows
        const vf4* hp = (const vf4*)hidden
                        + (size_t)(b * Mn + mh * 128 + mg * 32) * (Hn / 4)
                        + kh * 32 + col;
        vf4 a0 = 0.f, a1 = 0.f, a2 = 0.f, a3 = 0.f;
#pragma unroll
        for (int m = 0; m < 32; m += 4) {
            vf4 v0 = __builtin_nontemporal_load(hp + (size_t)(m + 0) * (Hn / 4));
            vf4 v1 = __builtin_nontemporal_load(hp + (size_t)(m + 1) * (Hn / 4));
            vf4 v2 = __builtin_nontemporal_load(hp + (size_t)(m + 2) * (Hn / 4));
            vf4 v3 = __builtin_nontemporal_load(hp + (size_t)(m + 3) * (Hn / 4));
            a0 += v0; a1 += v1; a2 += v2; a3 += v3;
        }
        vf4 s = (a0 + a1) + (a2 + a3);
        __shared__ vf4 sd[4][32];
        sd[mg][col] = s;
        __syncthreads();
        if (t < 32) {
            vf4 r = (sd[0][t] + sd[1][t]) + (sd[2][t] + sd[3][t]);
            ((vf4*)hsp)[(size_t)(mh * Bn + b) * (Hn / 4) + kh * 32 + t] = r;
        }
    } else {
        // 4096 waves total; wave w handles rows [4w, 4w+4) of the E*Hn row space
        const int wave = (bid - 256) * 2 + (t >> 6);
        const int lane = t & 63;
        const size_t r0 = (size_t)wave * 4;
        const vf4* base = (const vf4*)gup;   // row r starts at base + r*512
        vf4 cur[8], nxt[8];
#pragma unroll
        for (int i = 0; i < 8; ++i)
            cur[i] = __builtin_nontemporal_load(base + r0 * 512 + i * 64 + lane);
        float rowsum[4];
#pragma unroll
        for (int j = 0; j < 4; ++j) {
            if (j < 3) {
#pragma unroll
                for (int i = 0; i < 8; ++i)
                    nxt[i] = __builtin_nontemporal_load(
                        base + (r0 + j + 1) * 512 + i * 64 + lane);
            }
            vf4 v = ((cur[0] + cur[1]) + (cur[2] + cur[3]))
                  + ((cur[4] + cur[5]) + (cur[6] + cur[7]));
            float s = (v.x + v.y) + (v.z + v.w);
#pragma unroll
            for (int off = 32; off > 0; off >>= 1)
                s += __shfl_down(s, off, 64);
            rowsum[j] = s;                 // valid on lane 0
            if (j < 3) {
#pragma unroll
                for (int i = 0; i < 8; ++i) cur[i] = nxt[i];
            }
        }
        if (lane == 0) {
            vf4 o = { rowsum[0], rowsum[1], rowsum[2], rowsum[3] };
            ((vf4*)wsum)[wave] = o;        // rows 4w..4w+3 contiguous
        }
    }
}

// out = sum_{b,e,k} sp[b,e] * (hspA[b,k]+hspB[b,k]) * wsum[e,k]
// single block, 1024 threads (16 waves) -- 192 KB of L2-hot reads
__global__ void __launch_bounds__(1024) final_kernel(
        const float* __restrict__ sparsity,
        const float* __restrict__ hsp,
        const float* __restrict__ wsum,
        float* __restrict__ out) {
    __shared__ float sp[Bn][En];
    __shared__ float red[16];
    const int t = threadIdx.x;
    if (t < Bn * En) {
        const int b = t >> 3, e = t & 7;
        sp[b][e] = sparsity[b * (Kn * En) + e];   // sparsity[0, b, 0, e]
    }
    __syncthreads();
    float acc = 0.f;
#pragma unroll
    for (int i = 0; i < Hn / 1024; ++i) {
        const int k = i * 1024 + t;
        float h[Bn];
#pragma unroll
        for (int b = 0; b < Bn; ++b)
            h[b] = hsp[b * Hn + k] + hsp[(Bn + b) * Hn + k];
#pragma unroll
        for (int e = 0; e < En; ++e) {
            float g = 0.f;
#pragma unroll
            for (int b = 0; b < Bn; ++b) g += sp[b][e] * h[b];
            acc += wsum[e * Hn + k] * g;
        }
    }
#pragma unroll
    for (int off = 32; off > 0; off >>= 1)
        acc += __shfl_down(acc, off, 64);
    const int lane = t & 63, wave = t >> 6;
    if (lane == 0) red[wave] = acc;
    __syncthreads();
    if (t == 0) {
        float r = 0.f;
#pragma unroll
        for (int w = 0; w < 16; ++w) r += red[w];
        out[0] = r;
    }
}

extern "C" void kernel_launch(void* const* d_in, const int* in_sizes, int n_in,
                              void* d_out, int out_size, void* d_ws, size_t ws_size,
                              hipStream_t stream) {
    const float* hidden   = (const float*)d_in[0];  // (1,8,256,2048) fp32
    const float* sparsity = (const float*)d_in[1];  // (1,8,2,8) fp32
    const float* gup      = (const float*)d_in[2];  // (1,8,2048,2048) fp32

    float* hsp  = (float*)d_ws;              // 2*Bn*Hn floats (128 KB)
    float* wsum = hsp + 2 * Bn * Hn;         // En*Hn floats (64 KB)

    reduce_kernel<<<2304, 128, 0, stream>>>(hidden, gup, hsp, wsum);
    final_kernel<<<1, 1024, 0, stream>>>(sparsity, hsp, wsum, (float*)d_out);
}